// Round 3
// baseline (305.931 us; speedup 1.0000x reference)
//
#include <hip/hip_runtime.h>

typedef __bf16 bf16x8 __attribute__((ext_vector_type(8)));
typedef float f32x4 __attribute__((ext_vector_type(4)));

#define SL2E 0.18033688011112042f  // log2(e)/8, folded into Q at gemm_qkv epilogue

__device__ __forceinline__ unsigned short f2bf(float f) {
  union { float f; unsigned u; } v; v.f = f;
  unsigned r = v.u + 0x7fffu + ((v.u >> 16) & 1u);
  return (unsigned short)(r >> 16);
}

__device__ __forceinline__ float fast_exp2(float x) {
#if __has_builtin(__builtin_amdgcn_exp2f)
  return __builtin_amdgcn_exp2f(x);
#else
  return exp2f(x);
#endif
}

__device__ __forceinline__ unsigned pack_bf2(float lo, float hi) {
  union { float f; unsigned u; } a, b;
  a.f = lo; b.f = hi;
#if __has_builtin(__builtin_amdgcn_perm)
  return __builtin_amdgcn_perm(b.u + 0x7fffu, a.u + 0x7fffu, 0x07060302u);
#else
  return ((b.u + 0x7fffu) & 0xffff0000u) | ((a.u + 0x7fffu) >> 16);
#endif
}

// async global->LDS, 16B per lane; LDS dest = wave-uniform base + lane*16
__device__ __forceinline__ void gload16(const unsigned short* g, unsigned short* l) {
  __builtin_amdgcn_global_load_lds(
      (const __attribute__((address_space(1))) unsigned int*)g,
      (__attribute__((address_space(3))) unsigned int*)l, 16, 0, 0);
}

// ---------------- fused fp32 -> bf16 conversion (x, w_qkv, w_out) ----------------
__global__ __launch_bounds__(256) void f32_to_bf16_all(
    const float* __restrict__ x, const float* __restrict__ wq, const float* __restrict__ wo,
    unsigned short* __restrict__ xb, unsigned short* __restrict__ wqb, unsigned short* __restrict__ wob) {
  int i = blockIdx.x * 256 + threadIdx.x;  // quad index
  const float* src; unsigned short* dst; int off;
  if (i < 2097152) { src = x; dst = xb; off = i; }
  else if (i < 2883584) { src = wq; dst = wqb; off = i - 2097152; }
  else if (i < 3145728) { src = wo; dst = wob; off = i - 2883584; }
  else return;
  float4 v = ((const float4*)src)[off];
  ushort4 o;
  o.x = f2bf(v.x); o.y = f2bf(v.y); o.z = f2bf(v.z); o.w = f2bf(v.w);
  ((ushort4*)dst)[off] = o;
}

// ---------------- GEMM1: qkv = x @ w_qkv^T + b, scatter to Q/K/Vt ----------------
// m97-style: global_load_lds(16B) staging into unpadded [128][32]-short tiles.
// t=0 -> Qb[b,h,s,d] (scaled by SL2E); t=1 -> Kb[b,h,s,d]; t=2 -> Vtb[b,h,d,s].
__global__ __launch_bounds__(256) void gemm_qkv(
    const unsigned short* __restrict__ A,
    const unsigned short* __restrict__ Bt,
    const float* __restrict__ bias,
    unsigned short* __restrict__ Qb,
    unsigned short* __restrict__ Kb,
    unsigned short* __restrict__ Vtb) {
  const int K = 1024;
  __shared__ unsigned short As[128 * 32];
  __shared__ unsigned short Bs[128 * 32];
  int tid = threadIdx.x;
  int m0 = blockIdx.x * 128, n0 = blockIdx.y * 128;
  int w = tid >> 6, lane = tid & 63, l15 = lane & 15, quad = lane >> 4;
  int wm = (w & 1) * 64, wn = (w >> 1) * 64;

  f32x4 acc[4][4] = {};

  // staging: wave w owns rows [w*32, w*32+32) of each tile; 2 instrs of 16 rows
  int srow = lane >> 2, scol = (lane & 3) * 8;
  const unsigned short* Ag0 = A + (m0 + w * 32 + srow) * K + scol;
  const unsigned short* Bg0 = Bt + (n0 + w * 32 + srow) * K + scol;
  unsigned short* Asl = As + w * 1024 + lane * 8;
  unsigned short* Bsl = Bs + w * 1024 + lane * 8;

  for (int kt = 0; kt < K; kt += 32) {
    __syncthreads();
    gload16(Ag0 + kt, Asl);
    gload16(Ag0 + 16 * K + kt, Asl + 512);
    gload16(Bg0 + kt, Bsl);
    gload16(Bg0 + 16 * K + kt, Bsl + 512);
    __syncthreads();
    bf16x8 af[4], bfr[4];
#pragma unroll
    for (int i = 0; i < 4; ++i) af[i] = *(const bf16x8*)(As + (wm + i * 16 + l15) * 32 + quad * 8);
#pragma unroll
    for (int j = 0; j < 4; ++j) bfr[j] = *(const bf16x8*)(Bs + (wn + j * 16 + l15) * 32 + quad * 8);
#pragma unroll
    for (int i = 0; i < 4; ++i)
#pragma unroll
      for (int j = 0; j < 4; ++j)
        acc[i][j] = __builtin_amdgcn_mfma_f32_16x16x32_bf16(af[i], bfr[j], acc[i][j], 0, 0, 0);
  }

  int b = m0 >> 12;
  int sblk = (m0 & 4095) + wm + quad * 4;
#pragma unroll
  for (int j = 0; j < 4; ++j) {
    int n_j = n0 + wn + j * 16 + l15;
    float bv = bias[n_j];
    int t = n_j >> 10, h = (n_j >> 6) & 15, d = n_j & 63;
    if (t == 2) {
      int vbase = ((b * 16 + h) * 64 + d) * 4096;
#pragma unroll
      for (int i = 0; i < 4; ++i) {
        int s = sblk + i * 16;
        ushort4 pk;
        pk.x = f2bf(acc[i][j][0] + bv);
        pk.y = f2bf(acc[i][j][1] + bv);
        pk.z = f2bf(acc[i][j][2] + bv);
        pk.w = f2bf(acc[i][j][3] + bv);
        *(ushort4*)(Vtb + vbase + s) = pk;
      }
    } else {
      unsigned short* dst = (t == 0) ? Qb : Kb;
      float sc = (t == 0) ? SL2E : 1.0f;
      int base = (b * 16 + h) * 4096 * 64 + d;
#pragma unroll
      for (int i = 0; i < 4; ++i)
#pragma unroll
        for (int r = 0; r < 4; ++r) {
          int s = sblk + i * 16 + r;
          dst[base + s * 64] = f2bf((acc[i][j][r] + bv) * sc);
        }
    }
  }
}

// ---------------- fused block-diagonal attention, 4x4-blocked ----------------
// block = (b, h, seg, 256-q chunk); 4 waves, each owns 64 q rows.
// S^T = mfma(A=K, B=Q) -> C-regs hold 4 consecutive k -> b64 P writes.
// P round-trip chunked to 16 q-rows/wave; row-sum l accumulated in VALU.
#define LDP 72

__global__ __launch_bounds__(256, 3) void attn_k(
    const unsigned short* __restrict__ Qb,
    const unsigned short* __restrict__ Kb,
    const unsigned short* __restrict__ Vtb,
    unsigned short* __restrict__ Ab) {
  __shared__ unsigned short Ks[64 * LDP];
  __shared__ unsigned short Vs[64 * LDP];
  __shared__ unsigned short Ps[4][16 * LDP];

  int tid = threadIdx.x;
  int idx = blockIdx.x;
  int qblk = idx & 3, seg = (idx >> 2) & 3, h = (idx >> 4) & 15, b = idx >> 8;
  int w = tid >> 6, lane = tid & 63, l15 = lane & 15, quad = lane >> 4;
  int bh = b * 16 + h;
  int q0 = seg * 1024 + qblk * 256 + w * 64;

  const unsigned short* Qg = Qb + (bh * 4096 + q0) * 64;
  bf16x8 qf[4][2];
#pragma unroll
  for (int qb = 0; qb < 4; ++qb)
#pragma unroll
    for (int kk = 0; kk < 2; ++kk)
      qf[qb][kk] = *(const bf16x8*)(Qg + (qb * 16 + l15) * 64 + kk * 32 + quad * 8);

  f32x4 o[4][4] = {};                 // [qb][db]
  float lsum[4] = {0.f, 0.f, 0.f, 0.f};  // per-lane partial row-sums (q = l15)
  unsigned short* Pw = Ps[w];

  int sr = tid >> 3;
  int sc = (tid & 7) * 8;
  const unsigned short* Kg = Kb + (bh * 4096 + seg * 1024) * 64;
  const unsigned short* Vg = Vtb + bh * 64 * 4096 + seg * 1024;

  for (int kt = 0; kt < 16; ++kt) {
    int s0 = kt * 64;
    __syncthreads();
    *(uint4*)(Ks + sr * LDP + sc)        = *(const uint4*)(Kg + (s0 + sr) * 64 + sc);
    *(uint4*)(Ks + (sr + 32) * LDP + sc) = *(const uint4*)(Kg + (s0 + sr + 32) * 64 + sc);
    *(uint4*)(Vs + sr * LDP + sc)        = *(const uint4*)(Vg + sr * 4096 + s0 + sc);
    *(uint4*)(Vs + (sr + 32) * LDP + sc) = *(const uint4*)(Vg + (sr + 32) * 4096 + s0 + sc);
    __syncthreads();

    // S phase: packed P fragments in registers
    uint2 pp[4][4];  // [qb][colgroup g = half*2+kb]
#pragma unroll
    for (int half = 0; half < 2; ++half) {
      f32x4 st[2][4] = {};
#pragma unroll
      for (int kk = 0; kk < 2; ++kk) {
        bf16x8 kf0 = *(const bf16x8*)(Ks + (half * 32 + l15) * LDP + kk * 32 + quad * 8);
        bf16x8 kf1 = *(const bf16x8*)(Ks + (half * 32 + 16 + l15) * LDP + kk * 32 + quad * 8);
#pragma unroll
        for (int qb = 0; qb < 4; ++qb) {
          st[0][qb] = __builtin_amdgcn_mfma_f32_16x16x32_bf16(kf0, qf[qb][kk], st[0][qb], 0, 0, 0);
          st[1][qb] = __builtin_amdgcn_mfma_f32_16x16x32_bf16(kf1, qf[qb][kk], st[1][qb], 0, 0, 0);
        }
      }
#pragma unroll
      for (int kb = 0; kb < 2; ++kb)
#pragma unroll
        for (int qb = 0; qb < 4; ++qb) {
          f32x4 s = st[kb][qb];
          float p0 = fast_exp2(s[0]), p1 = fast_exp2(s[1]);
          float p2 = fast_exp2(s[2]), p3 = fast_exp2(s[3]);
          lsum[qb] += (p0 + p1) + (p2 + p3);
          uint2 d;
          d.x = pack_bf2(p0, p1);
          d.y = pack_bf2(p2, p3);
          pp[qb][half * 2 + kb] = d;
        }
    }

    // PV phase: per-qb P chunk round-trip (wave-private, in-order DS)
    bf16x8 vf[2][4];
#pragma unroll
    for (int kk = 0; kk < 2; ++kk)
#pragma unroll
      for (int db = 0; db < 4; ++db)
        vf[kk][db] = *(const bf16x8*)(Vs + (db * 16 + l15) * LDP + kk * 32 + quad * 8);
#pragma unroll
    for (int qb = 0; qb < 4; ++qb) {
#pragma unroll
      for (int g = 0; g < 4; ++g)
        *(uint2*)(Pw + l15 * LDP + g * 16 + quad * 4) = pp[qb][g];
#pragma unroll
      for (int kk = 0; kk < 2; ++kk) {
        bf16x8 pa = *(const bf16x8*)(Pw + l15 * LDP + kk * 32 + quad * 8);
#pragma unroll
        for (int db = 0; db < 4; ++db)
          o[qb][db] = __builtin_amdgcn_mfma_f32_16x16x32_bf16(pa, vf[kk][db], o[qb][db], 0, 0, 0);
      }
    }
  }

  // reduce lsum over quads (each lane then holds l(q = l15))
#pragma unroll
  for (int qb = 0; qb < 4; ++qb) {
    lsum[qb] += __shfl_xor(lsum[qb], 16);
    lsum[qb] += __shfl_xor(lsum[qb], 32);
  }
  // transpose l from q=l15 indexing to q=quad*4+r via wave-private LDS
  float* Pf = (float*)Ps[w];
  if (quad == 0) {
#pragma unroll
    for (int qb = 0; qb < 4; ++qb) Pf[qb * 16 + l15] = lsum[qb];
  }
#pragma unroll
  for (int qb = 0; qb < 4; ++qb)
#pragma unroll
    for (int r = 0; r < 4; ++r) {
      float inv = 1.0f / Pf[qb * 16 + quad * 4 + r];
      int sg = q0 + qb * 16 + quad * 4 + r;
      int base = (b * 4096 + sg) * 1024 + h * 64;
#pragma unroll
      for (int db = 0; db < 4; ++db)
        Ab[base + db * 16 + l15] = f2bf(o[qb][db][r] * inv);
    }
}

// ---------------- GEMM2: out = Ab @ w_out^T + b_out (fp32 out) ----------------
__global__ __launch_bounds__(256) void gemm_out(
    const unsigned short* __restrict__ A,
    const unsigned short* __restrict__ Bt,
    const float* __restrict__ bias,
    float* __restrict__ C) {
  const int K = 1024;
  __shared__ unsigned short As[128 * 32];
  __shared__ unsigned short Bs[128 * 32];
  int tid = threadIdx.x;
  int m0 = blockIdx.x * 128, n0 = blockIdx.y * 128;
  int w = tid >> 6, lane = tid & 63, l15 = lane & 15, quad = lane >> 4;
  int wm = (w & 1) * 64, wn = (w >> 1) * 64;

  f32x4 acc[4][4] = {};

  int srow = lane >> 2, scol = (lane & 3) * 8;
  const unsigned short* Ag0 = A + (m0 + w * 32 + srow) * K + scol;
  const unsigned short* Bg0 = Bt + (n0 + w * 32 + srow) * K + scol;
  unsigned short* Asl = As + w * 1024 + lane * 8;
  unsigned short* Bsl = Bs + w * 1024 + lane * 8;

  for (int kt = 0; kt < K; kt += 32) {
    __syncthreads();
    gload16(Ag0 + kt, Asl);
    gload16(Ag0 + 16 * K + kt, Asl + 512);
    gload16(Bg0 + kt, Bsl);
    gload16(Bg0 + 16 * K + kt, Bsl + 512);
    __syncthreads();
    bf16x8 af[4], bfr[4];
#pragma unroll
    for (int i = 0; i < 4; ++i) af[i] = *(const bf16x8*)(As + (wm + i * 16 + l15) * 32 + quad * 8);
#pragma unroll
    for (int j = 0; j < 4; ++j) bfr[j] = *(const bf16x8*)(Bs + (wn + j * 16 + l15) * 32 + quad * 8);
#pragma unroll
    for (int i = 0; i < 4; ++i)
#pragma unroll
      for (int j = 0; j < 4; ++j)
        acc[i][j] = __builtin_amdgcn_mfma_f32_16x16x32_bf16(af[i], bfr[j], acc[i][j], 0, 0, 0);
  }

#pragma unroll
  for (int j = 0; j < 4; ++j) {
    int n_j = n0 + wn + j * 16 + l15;
    float bv = bias[n_j];
#pragma unroll
    for (int i = 0; i < 4; ++i)
#pragma unroll
      for (int r = 0; r < 4; ++r) {
        int m = m0 + wm + i * 16 + quad * 4 + r;
        C[m * 1024 + n_j] = acc[i][j][r] + bv;
      }
  }
}

// ---------------- launch ----------------
extern "C" void kernel_launch(void* const* d_in, const int* in_sizes, int n_in,
                              void* d_out, int out_size, void* d_ws, size_t ws_size,
                              hipStream_t stream) {
  const float* x     = (const float*)d_in[0];
  const float* w_qkv = (const float*)d_in[1];
  const float* b_qkv = (const float*)d_in[2];
  const float* w_out = (const float*)d_in[3];
  const float* b_out = (const float*)d_in[4];
  float* out = (float*)d_out;
  char* ws = (char*)d_ws;

  unsigned short* wqkvb = (unsigned short*)(ws);              //  6 MB [3072][1024]
  unsigned short* woutb = (unsigned short*)(ws + 6291456);    //  2 MB [1024][1024]
  unsigned short* Qb    = (unsigned short*)(ws + 8388608);    // 16 MB [b,h,s,d] (x SL2E)
  unsigned short* Kb    = (unsigned short*)(ws + 25165824);   // 16 MB [b,h,s,d]
  unsigned short* Vtb   = (unsigned short*)(ws + 41943040);   // 16 MB [b,h,d,s]
  unsigned short* xb    = (unsigned short*)(ws + 58720256);   // 16 MB (reused as Ab)
  unsigned short* Ab    = xb;

  f32_to_bf16_all<<<12288, 256, 0, stream>>>(x, w_qkv, w_out, xb, wqkvb, woutb);
  gemm_qkv<<<dim3(64, 24), 256, 0, stream>>>(xb, wqkvb, b_qkv, Qb, Kb, Vtb);
  attn_k<<<512, 256, 0, stream>>>(Qb, Kb, Vtb, Ab);
  gemm_out<<<dim3(64, 8), 256, 0, stream>>>(Ab, woutb, b_out, out);
}

// Round 4
// 259.811 us; speedup vs baseline: 1.1775x; 1.1775x over previous
//
#include <hip/hip_runtime.h>

typedef __bf16 bf16x8 __attribute__((ext_vector_type(8)));
typedef float f32x4 __attribute__((ext_vector_type(4)));

#define SL2E 0.18033688011112042f  // log2(e)/8, folded into Q at gemm_qkv epilogue

__device__ __forceinline__ unsigned short f2bf(float f) {
  union { float f; unsigned u; } v; v.f = f;
  unsigned r = v.u + 0x7fffu + ((v.u >> 16) & 1u);
  return (unsigned short)(r >> 16);
}

__device__ __forceinline__ float fast_exp2(float x) {
#if __has_builtin(__builtin_amdgcn_exp2f)
  return __builtin_amdgcn_exp2f(x);
#else
  return exp2f(x);
#endif
}

__device__ __forceinline__ unsigned pack_bf2(float lo, float hi) {
  union { float f; unsigned u; } a, b;
  a.f = lo; b.f = hi;
#if __has_builtin(__builtin_amdgcn_perm)
  return __builtin_amdgcn_perm(b.u + 0x7fffu, a.u + 0x7fffu, 0x07060302u);
#else
  return ((b.u + 0x7fffu) & 0xffff0000u) | ((a.u + 0x7fffu) >> 16);
#endif
}

// async global->LDS, 16B/lane; LDS dest = wave-uniform base + lane*16
__device__ __forceinline__ void gload16(const unsigned short* g, unsigned short* l) {
  __builtin_amdgcn_global_load_lds(
      (const __attribute__((address_space(1))) unsigned int*)g,
      (__attribute__((address_space(3))) unsigned int*)l, 16, 0, 0);
}

// ---------------- fused fp32 -> bf16 conversion (x, w_qkv, w_out) ----------------
__global__ __launch_bounds__(256) void f32_to_bf16_all(
    const float* __restrict__ x, const float* __restrict__ wq, const float* __restrict__ wo,
    unsigned short* __restrict__ xb, unsigned short* __restrict__ wqb, unsigned short* __restrict__ wob) {
  int i = blockIdx.x * 256 + threadIdx.x;  // quad index
  const float* src; unsigned short* dst; int off;
  if (i < 2097152) { src = x; dst = xb; off = i; }
  else if (i < 2883584) { src = wq; dst = wqb; off = i - 2097152; }
  else if (i < 3145728) { src = wo; dst = wob; off = i - 2883584; }
  else return;
  float4 v = ((const float4*)src)[off];
  ushort4 o;
  o.x = f2bf(v.x); o.y = f2bf(v.y); o.z = f2bf(v.z); o.w = f2bf(v.w);
  ((ushort4*)dst)[off] = o;
}

// ---------------- GEMM1 (round-2 measured structure): qkv = x @ w_qkv^T + b ----------------
// t=0 -> Qb[b,h,s,d] (scaled by SL2E); t=1 -> Kb[b,h,s,d]; t=2 -> Vtb[b,h,d,s].
__global__ __launch_bounds__(256) void gemm_qkv(
    const unsigned short* __restrict__ A,
    const unsigned short* __restrict__ Bt,
    const float* __restrict__ bias,
    unsigned short* __restrict__ Qb,
    unsigned short* __restrict__ Kb,
    unsigned short* __restrict__ Vtb) {
  const int K = 1024;
  __shared__ unsigned short As[128 * 40];
  __shared__ unsigned short Bs[128 * 40];
  int tid = threadIdx.x;
  int m0 = blockIdx.x * 128, n0 = blockIdx.y * 128;
  int w = tid >> 6, lane = tid & 63, l15 = lane & 15, quad = lane >> 4;
  int wm = (w & 1) * 64, wn = (w >> 1) * 64;

  f32x4 acc[4][4] = {};

  int c0 = tid, c1 = tid + 256;
  int ra0 = c0 >> 2, ca0 = (c0 & 3) * 8;
  int ra1 = c1 >> 2, ca1 = (c1 & 3) * 8;

  for (int kt = 0; kt < K; kt += 32) {
    __syncthreads();
    uint4 a0 = *(const uint4*)(A + (m0 + ra0) * K + kt + ca0);
    uint4 a1 = *(const uint4*)(A + (m0 + ra1) * K + kt + ca1);
    uint4 b0 = *(const uint4*)(Bt + (n0 + ra0) * K + kt + ca0);
    uint4 b1 = *(const uint4*)(Bt + (n0 + ra1) * K + kt + ca1);
    *(uint4*)(As + ra0 * 40 + ca0) = a0;
    *(uint4*)(As + ra1 * 40 + ca1) = a1;
    *(uint4*)(Bs + ra0 * 40 + ca0) = b0;
    *(uint4*)(Bs + ra1 * 40 + ca1) = b1;
    __syncthreads();
    bf16x8 af[4], bfr[4];
#pragma unroll
    for (int i = 0; i < 4; ++i) af[i] = *(const bf16x8*)(As + (wm + i * 16 + l15) * 40 + quad * 8);
#pragma unroll
    for (int j = 0; j < 4; ++j) bfr[j] = *(const bf16x8*)(Bs + (wn + j * 16 + l15) * 40 + quad * 8);
#pragma unroll
    for (int i = 0; i < 4; ++i)
#pragma unroll
      for (int j = 0; j < 4; ++j)
        acc[i][j] = __builtin_amdgcn_mfma_f32_16x16x32_bf16(af[i], bfr[j], acc[i][j], 0, 0, 0);
  }

  int b = m0 >> 12;
  int sblk = (m0 & 4095) + wm + quad * 4;
#pragma unroll
  for (int j = 0; j < 4; ++j) {
    int n_j = n0 + wn + j * 16 + l15;
    float bv = bias[n_j];
    int t = n_j >> 10, h = (n_j >> 6) & 15, d = n_j & 63;
    if (t == 2) {
      int vbase = ((b * 16 + h) * 64 + d) * 4096;
#pragma unroll
      for (int i = 0; i < 4; ++i) {
        int s = sblk + i * 16;
        ushort4 pk;
        pk.x = f2bf(acc[i][j][0] + bv);
        pk.y = f2bf(acc[i][j][1] + bv);
        pk.z = f2bf(acc[i][j][2] + bv);
        pk.w = f2bf(acc[i][j][3] + bv);
        *(ushort4*)(Vtb + vbase + s) = pk;
      }
    } else {
      unsigned short* dst = (t == 0) ? Qb : Kb;
      float sc = (t == 0) ? SL2E : 1.0f;
      int base = (b * 16 + h) * 4096 * 64 + d;
#pragma unroll
      for (int i = 0; i < 4; ++i)
#pragma unroll
        for (int r = 0; r < 4; ++r) {
          int s = sblk + i * 16 + r;
          dst[base + s * 64] = f2bf((acc[i][j][r] + bv) * sc);
        }
    }
  }
}

// ---------------- fused block-diagonal attention ----------------
// grid: idx = qblk*128 + grp  (qblk in HIGH bits -> same (b,h,seg) group shares XCD)
// double-buffered async K/V staging (global_load_lds, XOR-swizzled LDS layout)
#define LDP 72

// swizzled tile element address (shorts): row r, col-group cg (8 shorts each)
#define SWZ(r, cg) ((((r) * 8) + ((cg) ^ ((r) & 7))) * 8)

__global__ __launch_bounds__(256) void attn_k(
    const unsigned short* __restrict__ Qb,
    const unsigned short* __restrict__ Kb,
    const unsigned short* __restrict__ Vtb,
    unsigned short* __restrict__ Ab) {
  __shared__ unsigned short KV[2][2][4096];  // [buf][0=K,1=V][64 rows x 64 cols swizzled]
  __shared__ unsigned short Ps[4][16 * LDP];

  int tid = threadIdx.x;
  int idx = blockIdx.x;
  int grp = idx & 127, qblk = idx >> 7;
  int seg = grp & 3, h = (grp >> 2) & 15, b = grp >> 6;
  int w = tid >> 6, lane = tid & 63, l15 = lane & 15, quad = lane >> 4;
  int bh = b * 16 + h;
  int q0 = seg * 1024 + qblk * 256 + w * 64;

  const unsigned short* Kg = Kb + (bh * 4096 + seg * 1024) * 64;
  const unsigned short* Vg = Vtb + bh * 64 * 4096 + seg * 1024;

  // per-lane staging source mapping (matches LDS slot = w*128 + i*64 + lane)
  int r0 = w * 16 + (lane >> 3);
  int cs = ((lane & 7) ^ (lane >> 3)) * 8;  // swizzled col offset, shorts

  // hoist Q B-frags from global ([b,h,s,d] is frag-row-major)
  const unsigned short* Qg = Qb + (bh * 4096 + q0) * 64;
  bf16x8 qf[4][2];
#pragma unroll
  for (int qb = 0; qb < 4; ++qb)
#pragma unroll
    for (int kk = 0; kk < 2; ++kk)
      qf[qb][kk] = *(const bf16x8*)(Qg + (qb * 16 + l15) * 64 + kk * 32 + quad * 8);

  f32x4 o[4][4] = {};
  float lsum[4] = {0.f, 0.f, 0.f, 0.f};
  unsigned short* Pw = Ps[w];

  // prologue: stage tile 0 into buf 0
  {
    unsigned short* dk = &KV[0][0][w * 1024];
    unsigned short* dv = &KV[0][1][w * 1024];
    gload16(Kg + r0 * 64 + cs, dk);
    gload16(Kg + (r0 + 8) * 64 + cs, dk + 512);
    gload16(Vg + r0 * 4096 + cs, dv);
    gload16(Vg + (r0 + 8) * 4096 + cs, dv + 512);
  }

#pragma unroll 2
  for (int kt = 0; kt < 16; ++kt) {
    int cur = kt & 1;
    __syncthreads();  // drains async loads for buf[cur]; hands off buf[cur^1]
    if (kt < 15) {
      unsigned short* dk = &KV[cur ^ 1][0][w * 1024];
      unsigned short* dv = &KV[cur ^ 1][1][w * 1024];
      const unsigned short* kN = Kg + (kt + 1) * 4096;
      const unsigned short* vN = Vg + (kt + 1) * 64;
      gload16(kN + r0 * 64 + cs, dk);
      gload16(kN + (r0 + 8) * 64 + cs, dk + 512);
      gload16(vN + r0 * 4096 + cs, dv);
      gload16(vN + (r0 + 8) * 4096 + cs, dv + 512);
    }
    const unsigned short* Kt = KV[cur][0];
    const unsigned short* Vt = KV[cur][1];

    // S phase
    uint2 pp[4][4];
#pragma unroll
    for (int half = 0; half < 2; ++half) {
      f32x4 st[2][4] = {};
#pragma unroll
      for (int kk = 0; kk < 2; ++kk) {
        int cg = kk * 4 + quad;
        bf16x8 kf0 = *(const bf16x8*)(Kt + SWZ(half * 32 + l15, cg));
        bf16x8 kf1 = *(const bf16x8*)(Kt + SWZ(half * 32 + 16 + l15, cg));
#pragma unroll
        for (int qb = 0; qb < 4; ++qb) {
          st[0][qb] = __builtin_amdgcn_mfma_f32_16x16x32_bf16(kf0, qf[qb][kk], st[0][qb], 0, 0, 0);
          st[1][qb] = __builtin_amdgcn_mfma_f32_16x16x32_bf16(kf1, qf[qb][kk], st[1][qb], 0, 0, 0);
        }
      }
#pragma unroll
      for (int kb = 0; kb < 2; ++kb)
#pragma unroll
        for (int qb = 0; qb < 4; ++qb) {
          f32x4 s = st[kb][qb];
          float p0 = fast_exp2(s[0]), p1 = fast_exp2(s[1]);
          float p2 = fast_exp2(s[2]), p3 = fast_exp2(s[3]);
          lsum[qb] += (p0 + p1) + (p2 + p3);
          uint2 d;
          d.x = pack_bf2(p0, p1);
          d.y = pack_bf2(p2, p3);
          pp[qb][half * 2 + kb] = d;
        }
    }

    // PV phase
    bf16x8 vf[2][4];
#pragma unroll
    for (int kk = 0; kk < 2; ++kk)
#pragma unroll
      for (int db = 0; db < 4; ++db)
        vf[kk][db] = *(const bf16x8*)(Vt + SWZ(db * 16 + l15, kk * 4 + quad));
#pragma unroll
    for (int qb = 0; qb < 4; ++qb) {
#pragma unroll
      for (int g = 0; g < 4; ++g)
        *(uint2*)(Pw + l15 * LDP + g * 16 + quad * 4) = pp[qb][g];
#pragma unroll
      for (int kk = 0; kk < 2; ++kk) {
        bf16x8 pa = *(const bf16x8*)(Pw + l15 * LDP + kk * 32 + quad * 8);
#pragma unroll
        for (int db = 0; db < 4; ++db)
          o[qb][db] = __builtin_amdgcn_mfma_f32_16x16x32_bf16(pa, vf[kk][db], o[qb][db], 0, 0, 0);
      }
    }
  }

  // quad-reduce lsum: afterwards every lane holds l for q-row = l15 of each qb
#pragma unroll
  for (int qb = 0; qb < 4; ++qb) {
    lsum[qb] += __shfl_xor(lsum[qb], 16);
    lsum[qb] += __shfl_xor(lsum[qb], 32);
  }

  // epilogue: stage o (unnormalized) in wave-private LDS, normalize at read
  // (inv index = l15 = read row), pack, coalesced 16B stores.
  // Waves use buf0 region (final compute read buf1), wave-private 4KB each.
  float* Wf = (float*)(&KV[0][0][0]) + w * 1024;
#pragma unroll
  for (int qb = 0; qb < 4; ++qb) {
#pragma unroll
    for (int db = 0; db < 4; ++db)
#pragma unroll
      for (int r = 0; r < 4; ++r)
        Wf[(quad * 4 + r) * 64 + db * 16 + l15] = o[qb][db][r];
    float inv = 1.0f / lsum[qb];
    float4 x0 = *(float4*)(Wf + l15 * 64 + quad * 8);
    float4 x1 = *(float4*)(Wf + l15 * 64 + quad * 8 + 4);
    float4 x2 = *(float4*)(Wf + l15 * 64 + (quad + 4) * 8);
    float4 x3 = *(float4*)(Wf + l15 * 64 + (quad + 4) * 8 + 4);
    uint4 u0, u1;
    u0.x = pack_bf2(x0.x * inv, x0.y * inv);
    u0.y = pack_bf2(x0.z * inv, x0.w * inv);
    u0.z = pack_bf2(x1.x * inv, x1.y * inv);
    u0.w = pack_bf2(x1.z * inv, x1.w * inv);
    u1.x = pack_bf2(x2.x * inv, x2.y * inv);
    u1.y = pack_bf2(x2.z * inv, x2.w * inv);
    u1.z = pack_bf2(x3.x * inv, x3.y * inv);
    u1.w = pack_bf2(x3.z * inv, x3.w * inv);
    int sg = q0 + qb * 16 + l15;
    int base = (b * 4096 + sg) * 1024 + h * 64;
    *(uint4*)(Ab + base + quad * 8) = u0;
    *(uint4*)(Ab + base + (quad + 4) * 8) = u1;
  }
}

// ---------------- GEMM2 (round-2 structure): out = Ab @ w_out^T + b_out ----------------
__global__ __launch_bounds__(256) void gemm_out(
    const unsigned short* __restrict__ A,
    const unsigned short* __restrict__ Bt,
    const float* __restrict__ bias,
    float* __restrict__ C) {
  const int K = 1024;
  __shared__ unsigned short As[128 * 40];
  __shared__ unsigned short Bs[128 * 40];
  int tid = threadIdx.x;
  int m0 = blockIdx.x * 128, n0 = blockIdx.y * 128;
  int w = tid >> 6, lane = tid & 63, l15 = lane & 15, quad = lane >> 4;
  int wm = (w & 1) * 64, wn = (w >> 1) * 64;

  f32x4 acc[4][4] = {};

  int c0 = tid, c1 = tid + 256;
  int ra0 = c0 >> 2, ca0 = (c0 & 3) * 8;
  int ra1 = c1 >> 2, ca1 = (c1 & 3) * 8;

  for (int kt = 0; kt < K; kt += 32) {
    __syncthreads();
    uint4 a0 = *(const uint4*)(A + (m0 + ra0) * K + kt + ca0);
    uint4 a1 = *(const uint4*)(A + (m0 + ra1) * K + kt + ca1);
    uint4 b0 = *(const uint4*)(Bt + (n0 + ra0) * K + kt + ca0);
    uint4 b1 = *(const uint4*)(Bt + (n0 + ra1) * K + kt + ca1);
    *(uint4*)(As + ra0 * 40 + ca0) = a0;
    *(uint4*)(As + ra1 * 40 + ca1) = a1;
    *(uint4*)(Bs + ra0 * 40 + ca0) = b0;
    *(uint4*)(Bs + ra1 * 40 + ca1) = b1;
    __syncthreads();
    bf16x8 af[4], bfr[4];
#pragma unroll
    for (int i = 0; i < 4; ++i) af[i] = *(const bf16x8*)(As + (wm + i * 16 + l15) * 40 + quad * 8);
#pragma unroll
    for (int j = 0; j < 4; ++j) bfr[j] = *(const bf16x8*)(Bs + (wn + j * 16 + l15) * 40 + quad * 8);
#pragma unroll
    for (int i = 0; i < 4; ++i)
#pragma unroll
      for (int j = 0; j < 4; ++j)
        acc[i][j] = __builtin_amdgcn_mfma_f32_16x16x32_bf16(af[i], bfr[j], acc[i][j], 0, 0, 0);
  }

#pragma unroll
  for (int j = 0; j < 4; ++j) {
    int n_j = n0 + wn + j * 16 + l15;
    float bv = bias[n_j];
#pragma unroll
    for (int i = 0; i < 4; ++i)
#pragma unroll
      for (int r = 0; r < 4; ++r) {
        int m = m0 + wm + i * 16 + quad * 4 + r;
        C[m * 1024 + n_j] = acc[i][j][r] + bv;
      }
  }
}

// ---------------- launch ----------------
extern "C" void kernel_launch(void* const* d_in, const int* in_sizes, int n_in,
                              void* d_out, int out_size, void* d_ws, size_t ws_size,
                              hipStream_t stream) {
  const float* x     = (const float*)d_in[0];
  const float* w_qkv = (const float*)d_in[1];
  const float* b_qkv = (const float*)d_in[2];
  const float* w_out = (const float*)d_in[3];
  const float* b_out = (const float*)d_in[4];
  float* out = (float*)d_out;
  char* ws = (char*)d_ws;

  unsigned short* wqkvb = (unsigned short*)(ws);              //  6 MB [3072][1024]
  unsigned short* woutb = (unsigned short*)(ws + 6291456);    //  2 MB [1024][1024]
  unsigned short* Qb    = (unsigned short*)(ws + 8388608);    // 16 MB [b,h,s,d] (x SL2E)
  unsigned short* Kb    = (unsigned short*)(ws + 25165824);   // 16 MB [b,h,s,d]
  unsigned short* Vtb   = (unsigned short*)(ws + 41943040);   // 16 MB [b,h,d,s]
  unsigned short* xb    = (unsigned short*)(ws + 58720256);   // 16 MB (reused as Ab)
  unsigned short* Ab    = xb;

  f32_to_bf16_all<<<12288, 256, 0, stream>>>(x, w_qkv, w_out, xb, wqkvb, woutb);
  gemm_qkv<<<dim3(64, 24), 256, 0, stream>>>(xb, wqkvb, b_qkv, Qb, Kb, Vtb);
  attn_k<<<512, 256, 0, stream>>>(Qb, Kb, Vtb, Ab);
  gemm_out<<<dim3(64, 8), 256, 0, stream>>>(Ab, woutb, b_out, out);
}

// Round 5
// 246.184 us; speedup vs baseline: 1.2427x; 1.0554x over previous
//
#include <hip/hip_runtime.h>

typedef __bf16 bf16x8 __attribute__((ext_vector_type(8)));
typedef float f32x4 __attribute__((ext_vector_type(4)));

#define SL2E 0.18033688011112042f  // log2(e)/8, folded into Q at gemm_qkv epilogue

__device__ __forceinline__ unsigned short f2bf(float f) {
  union { float f; unsigned u; } v; v.f = f;
  unsigned r = v.u + 0x7fffu + ((v.u >> 16) & 1u);
  return (unsigned short)(r >> 16);
}

__device__ __forceinline__ float fast_exp2(float x) {
#if __has_builtin(__builtin_amdgcn_exp2f)
  return __builtin_amdgcn_exp2f(x);
#else
  return exp2f(x);
#endif
}

__device__ __forceinline__ unsigned pack_bf2(float lo, float hi) {
  union { float f; unsigned u; } a, b;
  a.f = lo; b.f = hi;
#if __has_builtin(__builtin_amdgcn_perm)
  return __builtin_amdgcn_perm(b.u + 0x7fffu, a.u + 0x7fffu, 0x07060302u);
#else
  return ((b.u + 0x7fffu) & 0xffff0000u) | ((a.u + 0x7fffu) >> 16);
#endif
}

// async global->LDS, 16B/lane; HW dest = readfirstlane(lds base) + lane*16
__device__ __forceinline__ void gload16(const unsigned short* g, unsigned short* l) {
  __builtin_amdgcn_global_load_lds(
      (const __attribute__((address_space(1))) unsigned int*)g,
      (__attribute__((address_space(3))) unsigned int*)l, 16, 0, 0);
}

// ---------------- fused fp32 -> bf16 conversion (x, w_qkv, w_out) ----------------
__global__ __launch_bounds__(256) void f32_to_bf16_all(
    const float* __restrict__ x, const float* __restrict__ wq, const float* __restrict__ wo,
    unsigned short* __restrict__ xb, unsigned short* __restrict__ wqb, unsigned short* __restrict__ wob) {
  int i = blockIdx.x * 256 + threadIdx.x;  // quad index
  const float* src; unsigned short* dst; int off;
  if (i < 2097152) { src = x; dst = xb; off = i; }
  else if (i < 2883584) { src = wq; dst = wqb; off = i - 2097152; }
  else if (i < 3145728) { src = wo; dst = wob; off = i - 2883584; }
  else return;
  float4 v = ((const float4*)src)[off];
  ushort4 o;
  o.x = f2bf(v.x); o.y = f2bf(v.y); o.z = f2bf(v.z); o.w = f2bf(v.w);
  ((ushort4*)dst)[off] = o;
}

// ============ swizzled-LDS m97-style GEMM core (128x128 tile, BK=32) ============
// LDS tile = 512 chunks of 16B; chunk(R,c) stored at p = R*4 + (c ^ ((R>>1)&3)).
// Frag read (row R, colgroup quad) -> addr R*32 + (quad ^ ((l15>>1)&3))*8 shorts:
// covers all 8 bank-groups exactly 2x per 16 lanes => conflict-free (2-way min).
// Staging: wave w owns chunks [w*128, w*128+128) = rows [w*32, w*32+32).

// ---------------- GEMM1: qkv = x @ w_qkv^T + b, scatter to Q/K/Vt ----------------
// t=0 -> Qb[b,h,s,d] (scaled by SL2E); t=1 -> Kb[b,h,s,d]; t=2 -> Vtb[b,h,d,s].
__global__ __launch_bounds__(256) void gemm_qkv(
    const unsigned short* __restrict__ A,
    const unsigned short* __restrict__ Bt,
    const float* __restrict__ bias,
    unsigned short* __restrict__ Qb,
    unsigned short* __restrict__ Kb,
    unsigned short* __restrict__ Vtb) {
  const int K = 1024;
  __shared__ unsigned short As[128 * 32];
  __shared__ unsigned short Bs[128 * 32];
  int tid = threadIdx.x;
  int m0 = blockIdx.x * 128, n0 = blockIdx.y * 128;
  int w = tid >> 6, lane = tid & 63, l15 = lane & 15, quad = lane >> 4;
  int wm = (w & 1) * 64, wn = (w >> 1) * 64;

  f32x4 acc[4][4] = {};

  // staging source mapping (inverse swizzle), loop-invariant per lane
  int p1 = w * 128 + lane, p2 = p1 + 64;
  int R1 = p1 >> 2, c1 = (p1 & 3) ^ ((p1 >> 3) & 3);
  int R2 = p2 >> 2, c2 = (p2 & 3) ^ ((p2 >> 3) & 3);
  const unsigned short* Ag1 = A + (m0 + R1) * K + c1 * 8;
  const unsigned short* Ag2 = A + (m0 + R2) * K + c2 * 8;
  const unsigned short* Bg1 = Bt + (n0 + R1) * K + c1 * 8;
  const unsigned short* Bg2 = Bt + (n0 + R2) * K + c2 * 8;
  unsigned short* Asl = As + w * 1024;
  unsigned short* Bsl = Bs + w * 1024;
  int sw = (quad ^ ((l15 >> 1) & 3)) * 8;  // swizzled colgroup offset for frag reads

  for (int kt = 0; kt < K; kt += 32) {
    __syncthreads();
    gload16(Ag1 + kt, Asl);
    gload16(Ag2 + kt, Asl + 512);
    gload16(Bg1 + kt, Bsl);
    gload16(Bg2 + kt, Bsl + 512);
    __syncthreads();
    bf16x8 af[4], bfr[4];
#pragma unroll
    for (int i = 0; i < 4; ++i) af[i] = *(const bf16x8*)(As + (wm + i * 16 + l15) * 32 + sw);
#pragma unroll
    for (int j = 0; j < 4; ++j) bfr[j] = *(const bf16x8*)(Bs + (wn + j * 16 + l15) * 32 + sw);
#pragma unroll
    for (int i = 0; i < 4; ++i)
#pragma unroll
      for (int j = 0; j < 4; ++j)
        acc[i][j] = __builtin_amdgcn_mfma_f32_16x16x32_bf16(af[i], bfr[j], acc[i][j], 0, 0, 0);
  }

  int b = m0 >> 12;
  int sblk = (m0 & 4095) + wm + quad * 4;
#pragma unroll
  for (int j = 0; j < 4; ++j) {
    int n_j = n0 + wn + j * 16 + l15;
    float bv = bias[n_j];
    int t = n_j >> 10, h = (n_j >> 6) & 15, d = n_j & 63;
    if (t == 2) {
      int vbase = ((b * 16 + h) * 64 + d) * 4096;
#pragma unroll
      for (int i = 0; i < 4; ++i) {
        int s = sblk + i * 16;
        ushort4 pk;
        pk.x = f2bf(acc[i][j][0] + bv);
        pk.y = f2bf(acc[i][j][1] + bv);
        pk.z = f2bf(acc[i][j][2] + bv);
        pk.w = f2bf(acc[i][j][3] + bv);
        *(ushort4*)(Vtb + vbase + s) = pk;
      }
    } else {
      unsigned short* dst = (t == 0) ? Qb : Kb;
      float sc = (t == 0) ? SL2E : 1.0f;
      int base = (b * 16 + h) * 4096 * 64 + d;
#pragma unroll
      for (int i = 0; i < 4; ++i)
#pragma unroll
        for (int r = 0; r < 4; ++r) {
          int s = sblk + i * 16 + r;
          dst[base + s * 64] = f2bf((acc[i][j][r] + bv) * sc);
        }
    }
  }
}

// ---------------- fused block-diagonal attention (round-4 measured state) ----------------
#define LDP 72
#define SWZ(r, cg) ((((r) * 8) + ((cg) ^ ((r) & 7))) * 8)

__global__ __launch_bounds__(256) void attn_k(
    const unsigned short* __restrict__ Qb,
    const unsigned short* __restrict__ Kb,
    const unsigned short* __restrict__ Vtb,
    unsigned short* __restrict__ Ab) {
  __shared__ unsigned short KV[2][2][4096];
  __shared__ unsigned short Ps[4][16 * LDP];

  int tid = threadIdx.x;
  int idx = blockIdx.x;
  int grp = idx & 127, qblk = idx >> 7;
  int seg = grp & 3, h = (grp >> 2) & 15, b = grp >> 6;
  int w = tid >> 6, lane = tid & 63, l15 = lane & 15, quad = lane >> 4;
  int bh = b * 16 + h;
  int q0 = seg * 1024 + qblk * 256 + w * 64;

  const unsigned short* Kg = Kb + (bh * 4096 + seg * 1024) * 64;
  const unsigned short* Vg = Vtb + bh * 64 * 4096 + seg * 1024;

  int r0 = w * 16 + (lane >> 3);
  int cs = ((lane & 7) ^ (lane >> 3)) * 8;

  const unsigned short* Qg = Qb + (bh * 4096 + q0) * 64;
  bf16x8 qf[4][2];
#pragma unroll
  for (int qb = 0; qb < 4; ++qb)
#pragma unroll
    for (int kk = 0; kk < 2; ++kk)
      qf[qb][kk] = *(const bf16x8*)(Qg + (qb * 16 + l15) * 64 + kk * 32 + quad * 8);

  f32x4 o[4][4] = {};
  float lsum[4] = {0.f, 0.f, 0.f, 0.f};
  unsigned short* Pw = Ps[w];

  {
    unsigned short* dk = &KV[0][0][w * 1024];
    unsigned short* dv = &KV[0][1][w * 1024];
    gload16(Kg + r0 * 64 + cs, dk);
    gload16(Kg + (r0 + 8) * 64 + cs, dk + 512);
    gload16(Vg + r0 * 4096 + cs, dv);
    gload16(Vg + (r0 + 8) * 4096 + cs, dv + 512);
  }

#pragma unroll 2
  for (int kt = 0; kt < 16; ++kt) {
    int cur = kt & 1;
    __syncthreads();
    if (kt < 15) {
      unsigned short* dk = &KV[cur ^ 1][0][w * 1024];
      unsigned short* dv = &KV[cur ^ 1][1][w * 1024];
      const unsigned short* kN = Kg + (kt + 1) * 4096;
      const unsigned short* vN = Vg + (kt + 1) * 64;
      gload16(kN + r0 * 64 + cs, dk);
      gload16(kN + (r0 + 8) * 64 + cs, dk + 512);
      gload16(vN + r0 * 4096 + cs, dv);
      gload16(vN + (r0 + 8) * 4096 + cs, dv + 512);
    }
    const unsigned short* Kt = KV[cur][0];
    const unsigned short* Vt = KV[cur][1];

    uint2 pp[4][4];
#pragma unroll
    for (int half = 0; half < 2; ++half) {
      f32x4 st[2][4] = {};
#pragma unroll
      for (int kk = 0; kk < 2; ++kk) {
        int cg = kk * 4 + quad;
        bf16x8 kf0 = *(const bf16x8*)(Kt + SWZ(half * 32 + l15, cg));
        bf16x8 kf1 = *(const bf16x8*)(Kt + SWZ(half * 32 + 16 + l15, cg));
#pragma unroll
        for (int qb = 0; qb < 4; ++qb) {
          st[0][qb] = __builtin_amdgcn_mfma_f32_16x16x32_bf16(kf0, qf[qb][kk], st[0][qb], 0, 0, 0);
          st[1][qb] = __builtin_amdgcn_mfma_f32_16x16x32_bf16(kf1, qf[qb][kk], st[1][qb], 0, 0, 0);
        }
      }
#pragma unroll
      for (int kb = 0; kb < 2; ++kb)
#pragma unroll
        for (int qb = 0; qb < 4; ++qb) {
          f32x4 s = st[kb][qb];
          float p0 = fast_exp2(s[0]), p1 = fast_exp2(s[1]);
          float p2 = fast_exp2(s[2]), p3 = fast_exp2(s[3]);
          lsum[qb] += (p0 + p1) + (p2 + p3);
          uint2 d;
          d.x = pack_bf2(p0, p1);
          d.y = pack_bf2(p2, p3);
          pp[qb][half * 2 + kb] = d;
        }
    }

    bf16x8 vf[2][4];
#pragma unroll
    for (int kk = 0; kk < 2; ++kk)
#pragma unroll
      for (int db = 0; db < 4; ++db)
        vf[kk][db] = *(const bf16x8*)(Vt + SWZ(db * 16 + l15, kk * 4 + quad));
#pragma unroll
    for (int qb = 0; qb < 4; ++qb) {
#pragma unroll
      for (int g = 0; g < 4; ++g)
        *(uint2*)(Pw + l15 * LDP + g * 16 + quad * 4) = pp[qb][g];
#pragma unroll
      for (int kk = 0; kk < 2; ++kk) {
        bf16x8 pa = *(const bf16x8*)(Pw + l15 * LDP + kk * 32 + quad * 8);
#pragma unroll
        for (int db = 0; db < 4; ++db)
          o[qb][db] = __builtin_amdgcn_mfma_f32_16x16x32_bf16(pa, vf[kk][db], o[qb][db], 0, 0, 0);
      }
    }
  }

#pragma unroll
  for (int qb = 0; qb < 4; ++qb) {
    lsum[qb] += __shfl_xor(lsum[qb], 16);
    lsum[qb] += __shfl_xor(lsum[qb], 32);
  }

  float* Wf = (float*)(&KV[0][0][0]) + w * 1024;
#pragma unroll
  for (int qb = 0; qb < 4; ++qb) {
#pragma unroll
    for (int db = 0; db < 4; ++db)
#pragma unroll
      for (int r = 0; r < 4; ++r)
        Wf[(quad * 4 + r) * 64 + db * 16 + l15] = o[qb][db][r];
    float inv = 1.0f / lsum[qb];
    float4 x0 = *(float4*)(Wf + l15 * 64 + quad * 8);
    float4 x1 = *(float4*)(Wf + l15 * 64 + quad * 8 + 4);
    float4 x2 = *(float4*)(Wf + l15 * 64 + (quad + 4) * 8);
    float4 x3 = *(float4*)(Wf + l15 * 64 + (quad + 4) * 8 + 4);
    uint4 u0, u1;
    u0.x = pack_bf2(x0.x * inv, x0.y * inv);
    u0.y = pack_bf2(x0.z * inv, x0.w * inv);
    u0.z = pack_bf2(x1.x * inv, x1.y * inv);
    u0.w = pack_bf2(x1.z * inv, x1.w * inv);
    u1.x = pack_bf2(x2.x * inv, x2.y * inv);
    u1.y = pack_bf2(x2.z * inv, x2.w * inv);
    u1.z = pack_bf2(x3.x * inv, x3.y * inv);
    u1.w = pack_bf2(x3.z * inv, x3.w * inv);
    int sg = q0 + qb * 16 + l15;
    int base = (b * 4096 + sg) * 1024 + h * 64;
    *(uint4*)(Ab + base + quad * 8) = u0;
    *(uint4*)(Ab + base + (quad + 4) * 8) = u1;
  }
}

// ---------------- GEMM2: out = Ab @ w_out^T + b_out (fp32 out) ----------------
__global__ __launch_bounds__(256) void gemm_out(
    const unsigned short* __restrict__ A,
    const unsigned short* __restrict__ Bt,
    const float* __restrict__ bias,
    float* __restrict__ C) {
  const int K = 1024;
  __shared__ unsigned short As[128 * 32];
  __shared__ unsigned short Bs[128 * 32];
  int tid = threadIdx.x;
  int m0 = blockIdx.x * 128, n0 = blockIdx.y * 128;
  int w = tid >> 6, lane = tid & 63, l15 = lane & 15, quad = lane >> 4;
  int wm = (w & 1) * 64, wn = (w >> 1) * 64;

  f32x4 acc[4][4] = {};

  int p1 = w * 128 + lane, p2 = p1 + 64;
  int R1 = p1 >> 2, c1 = (p1 & 3) ^ ((p1 >> 3) & 3);
  int R2 = p2 >> 2, c2 = (p2 & 3) ^ ((p2 >> 3) & 3);
  const unsigned short* Ag1 = A + (m0 + R1) * K + c1 * 8;
  const unsigned short* Ag2 = A + (m0 + R2) * K + c2 * 8;
  const unsigned short* Bg1 = Bt + (n0 + R1) * K + c1 * 8;
  const unsigned short* Bg2 = Bt + (n0 + R2) * K + c2 * 8;
  unsigned short* Asl = As + w * 1024;
  unsigned short* Bsl = Bs + w * 1024;
  int sw = (quad ^ ((l15 >> 1) & 3)) * 8;

  for (int kt = 0; kt < K; kt += 32) {
    __syncthreads();
    gload16(Ag1 + kt, Asl);
    gload16(Ag2 + kt, Asl + 512);
    gload16(Bg1 + kt, Bsl);
    gload16(Bg2 + kt, Bsl + 512);
    __syncthreads();
    bf16x8 af[4], bfr[4];
#pragma unroll
    for (int i = 0; i < 4; ++i) af[i] = *(const bf16x8*)(As + (wm + i * 16 + l15) * 32 + sw);
#pragma unroll
    for (int j = 0; j < 4; ++j) bfr[j] = *(const bf16x8*)(Bs + (wn + j * 16 + l15) * 32 + sw);
#pragma unroll
    for (int i = 0; i < 4; ++i)
#pragma unroll
      for (int j = 0; j < 4; ++j)
        acc[i][j] = __builtin_amdgcn_mfma_f32_16x16x32_bf16(af[i], bfr[j], acc[i][j], 0, 0, 0);
  }

#pragma unroll
  for (int j = 0; j < 4; ++j) {
    int n_j = n0 + wn + j * 16 + l15;
    float bv = bias[n_j];
#pragma unroll
    for (int i = 0; i < 4; ++i)
#pragma unroll
      for (int r = 0; r < 4; ++r) {
        int m = m0 + wm + i * 16 + quad * 4 + r;
        C[m * 1024 + n_j] = acc[i][j][r] + bv;
      }
  }
}

// ---------------- launch ----------------
extern "C" void kernel_launch(void* const* d_in, const int* in_sizes, int n_in,
                              void* d_out, int out_size, void* d_ws, size_t ws_size,
                              hipStream_t stream) {
  const float* x     = (const float*)d_in[0];
  const float* w_qkv = (const float*)d_in[1];
  const float* b_qkv = (const float*)d_in[2];
  const float* w_out = (const float*)d_in[3];
  const float* b_out = (const float*)d_in[4];
  float* out = (float*)d_out;
  char* ws = (char*)d_ws;

  unsigned short* wqkvb = (unsigned short*)(ws);              //  6 MB [3072][1024]
  unsigned short* woutb = (unsigned short*)(ws + 6291456);    //  2 MB [1024][1024]
  unsigned short* Qb    = (unsigned short*)(ws + 8388608);    // 16 MB [b,h,s,d] (x SL2E)
  unsigned short* Kb    = (unsigned short*)(ws + 25165824);   // 16 MB [b,h,s,d]
  unsigned short* Vtb   = (unsigned short*)(ws + 41943040);   // 16 MB [b,h,d,s]
  unsigned short* xb    = (unsigned short*)(ws + 58720256);   // 16 MB (reused as Ab)
  unsigned short* Ab    = xb;

  f32_to_bf16_all<<<12288, 256, 0, stream>>>(x, w_qkv, w_out, xb, wqkvb, woutb);
  gemm_qkv<<<dim3(64, 24), 256, 0, stream>>>(xb, wqkvb, b_qkv, Qb, Kb, Vtb);
  attn_k<<<512, 256, 0, stream>>>(Qb, Kb, Vtb, Ab);
  gemm_out<<<dim3(64, 8), 256, 0, stream>>>(Ab, woutb, b_out, out);
}

// Round 6
// 228.819 us; speedup vs baseline: 1.3370x; 1.0759x over previous
//
#include <hip/hip_runtime.h>

typedef __bf16 bf16x8 __attribute__((ext_vector_type(8)));
typedef float f32x4 __attribute__((ext_vector_type(4)));

#define SL2E 0.18033688011112042f  // log2(e)/8, folded into Q at gemm_qkv epilogue

__device__ __forceinline__ unsigned short f2bf(float f) {
  union { float f; unsigned u; } v; v.f = f;
  unsigned r = v.u + 0x7fffu + ((v.u >> 16) & 1u);
  return (unsigned short)(r >> 16);
}

__device__ __forceinline__ float fast_exp2(float x) {
#if __has_builtin(__builtin_amdgcn_exp2f)
  return __builtin_amdgcn_exp2f(x);
#else
  return exp2f(x);
#endif
}

__device__ __forceinline__ unsigned pack_bf2(float lo, float hi) {
  union { float f; unsigned u; } a, b;
  a.f = lo; b.f = hi;
#if __has_builtin(__builtin_amdgcn_perm)
  return __builtin_amdgcn_perm(b.u + 0x7fffu, a.u + 0x7fffu, 0x07060302u);
#else
  return ((b.u + 0x7fffu) & 0xffff0000u) | ((a.u + 0x7fffu) >> 16);
#endif
}

// async global->LDS, 16B/lane; HW dest = readfirstlane(lds base) + lane*16
__device__ __forceinline__ void gload16(const unsigned short* g, unsigned short* l) {
  __builtin_amdgcn_global_load_lds(
      (const __attribute__((address_space(1))) unsigned int*)g,
      (__attribute__((address_space(3))) unsigned int*)l, 16, 0, 0);
}

// ---------------- fused fp32 -> bf16 conversion (x, w_qkv, w_out) ----------------
__global__ __launch_bounds__(256) void f32_to_bf16_all(
    const float* __restrict__ x, const float* __restrict__ wq, const float* __restrict__ wo,
    unsigned short* __restrict__ xb, unsigned short* __restrict__ wqb, unsigned short* __restrict__ wob) {
  int i = blockIdx.x * 256 + threadIdx.x;  // quad index
  const float* src; unsigned short* dst; int off;
  if (i < 2097152) { src = x; dst = xb; off = i; }
  else if (i < 2883584) { src = wq; dst = wqb; off = i - 2097152; }
  else if (i < 3145728) { src = wo; dst = wob; off = i - 2883584; }
  else return;
  float4 v = ((const float4*)src)[off];
  ushort4 o;
  o.x = f2bf(v.x); o.y = f2bf(v.y); o.z = f2bf(v.z); o.w = f2bf(v.w);
  ((ushort4*)dst)[off] = o;
}

// ============ swizzled-LDS GEMM core, 128x128 tile, BK=64 (32KB LDS) ============
// Tile = 128 rows x 8 colgroups of 16B; chunk(R,c) at p = R*8 + (c ^ (R&7)).
// Frag read (row R=.. +l15, cg=kk*4+quad): addr R*64 + ((cg ^ (l15&7))*8) shorts
// -> 8 lanes per 4-bank group = uniform = zero extra conflict cycles (measured-0
// pattern from round 5 generalized). Staging: wave w owns chunks [w*256,+256) =
// rows [w*32,+32); per-lane source col is loop-invariant: cs=((lane&7)^(lane>>3))*8.

// ---------------- GEMM1: qkv = x @ w_qkv^T + b, scatter to Q/K/Vt ----------------
__global__ __launch_bounds__(256) void gemm_qkv(
    const unsigned short* __restrict__ A,
    const unsigned short* __restrict__ Bt,
    const float* __restrict__ bias,
    unsigned short* __restrict__ Qb,
    unsigned short* __restrict__ Kb,
    unsigned short* __restrict__ Vtb) {
  const int K = 1024;
  __shared__ unsigned short As[128 * 64];
  __shared__ unsigned short Bs[128 * 64];
  int tid = threadIdx.x;
  int m0 = blockIdx.x * 128, n0 = blockIdx.y * 128;
  int w = tid >> 6, lane = tid & 63, l15 = lane & 15, quad = lane >> 4;
  int wm = (w & 1) * 64, wn = (w >> 1) * 64;

  f32x4 acc[4][4] = {};

  // staging source mapping (inverse swizzle), loop-invariant per lane
  int rs = w * 32 + (lane >> 3);                 // row for i=0; +8 per instr
  int cs = ((lane & 7) ^ (lane >> 3)) * 8;       // swizzled col offset (shorts)
  const unsigned short* Ag = A + (m0 + rs) * K + cs;
  const unsigned short* Bg = Bt + (n0 + rs) * K + cs;
  unsigned short* Asl = As + w * 2048;
  unsigned short* Bsl = Bs + w * 2048;

  for (int kt = 0; kt < K; kt += 64) {
    __syncthreads();
#pragma unroll
    for (int i = 0; i < 4; ++i) {
      gload16(Ag + i * 8 * K + kt, Asl + i * 512);
      gload16(Bg + i * 8 * K + kt, Bsl + i * 512);
    }
    __syncthreads();
#pragma unroll
    for (int kk = 0; kk < 2; ++kk) {
      int swk = (((kk * 4 + quad) ^ (l15 & 7))) * 8;
      bf16x8 af[4], bfr[4];
#pragma unroll
      for (int i = 0; i < 4; ++i) af[i] = *(const bf16x8*)(As + (wm + i * 16 + l15) * 64 + swk);
#pragma unroll
      for (int j = 0; j < 4; ++j) bfr[j] = *(const bf16x8*)(Bs + (wn + j * 16 + l15) * 64 + swk);
#pragma unroll
      for (int i = 0; i < 4; ++i)
#pragma unroll
        for (int j = 0; j < 4; ++j)
          acc[i][j] = __builtin_amdgcn_mfma_f32_16x16x32_bf16(af[i], bfr[j], acc[i][j], 0, 0, 0);
    }
  }

  int b = m0 >> 12;
  int sblk = (m0 & 4095) + wm + quad * 4;
#pragma unroll
  for (int j = 0; j < 4; ++j) {
    int n_j = n0 + wn + j * 16 + l15;
    float bv = bias[n_j];
    int t = n_j >> 10, h = (n_j >> 6) & 15, d = n_j & 63;
    if (t == 2) {
      int vbase = ((b * 16 + h) * 64 + d) * 4096;
#pragma unroll
      for (int i = 0; i < 4; ++i) {
        int s = sblk + i * 16;
        ushort4 pk;
        pk.x = f2bf(acc[i][j][0] + bv);
        pk.y = f2bf(acc[i][j][1] + bv);
        pk.z = f2bf(acc[i][j][2] + bv);
        pk.w = f2bf(acc[i][j][3] + bv);
        *(ushort4*)(Vtb + vbase + s) = pk;
      }
    } else {
      unsigned short* dst = (t == 0) ? Qb : Kb;
      float sc = (t == 0) ? SL2E : 1.0f;
      int base = (b * 16 + h) * 4096 * 64 + d;
#pragma unroll
      for (int i = 0; i < 4; ++i)
#pragma unroll
        for (int r = 0; r < 4; ++r) {
          int s = sblk + i * 16 + r;
          dst[base + s * 64] = f2bf((acc[i][j][r] + bv) * sc);
        }
    }
  }
}

// ---------------- fused block-diagonal attention (round-4 measured state) ----------------
#define LDP 72
#define SWZ(r, cg) ((((r) * 8) + ((cg) ^ ((r) & 7))) * 8)

__global__ __launch_bounds__(256) void attn_k(
    const unsigned short* __restrict__ Qb,
    const unsigned short* __restrict__ Kb,
    const unsigned short* __restrict__ Vtb,
    unsigned short* __restrict__ Ab) {
  __shared__ unsigned short KV[2][2][4096];
  __shared__ unsigned short Ps[4][16 * LDP];

  int tid = threadIdx.x;
  int idx = blockIdx.x;
  int grp = idx & 127, qblk = idx >> 7;
  int seg = grp & 3, h = (grp >> 2) & 15, b = grp >> 6;
  int w = tid >> 6, lane = tid & 63, l15 = lane & 15, quad = lane >> 4;
  int bh = b * 16 + h;
  int q0 = seg * 1024 + qblk * 256 + w * 64;

  const unsigned short* Kg = Kb + (bh * 4096 + seg * 1024) * 64;
  const unsigned short* Vg = Vtb + bh * 64 * 4096 + seg * 1024;

  int r0 = w * 16 + (lane >> 3);
  int cs = ((lane & 7) ^ (lane >> 3)) * 8;

  const unsigned short* Qg = Qb + (bh * 4096 + q0) * 64;
  bf16x8 qf[4][2];
#pragma unroll
  for (int qb = 0; qb < 4; ++qb)
#pragma unroll
    for (int kk = 0; kk < 2; ++kk)
      qf[qb][kk] = *(const bf16x8*)(Qg + (qb * 16 + l15) * 64 + kk * 32 + quad * 8);

  f32x4 o[4][4] = {};
  float lsum[4] = {0.f, 0.f, 0.f, 0.f};
  unsigned short* Pw = Ps[w];

  {
    unsigned short* dk = &KV[0][0][w * 1024];
    unsigned short* dv = &KV[0][1][w * 1024];
    gload16(Kg + r0 * 64 + cs, dk);
    gload16(Kg + (r0 + 8) * 64 + cs, dk + 512);
    gload16(Vg + r0 * 4096 + cs, dv);
    gload16(Vg + (r0 + 8) * 4096 + cs, dv + 512);
  }

#pragma unroll 2
  for (int kt = 0; kt < 16; ++kt) {
    int cur = kt & 1;
    __syncthreads();
    if (kt < 15) {
      unsigned short* dk = &KV[cur ^ 1][0][w * 1024];
      unsigned short* dv = &KV[cur ^ 1][1][w * 1024];
      const unsigned short* kN = Kg + (kt + 1) * 4096;
      const unsigned short* vN = Vg + (kt + 1) * 64;
      gload16(kN + r0 * 64 + cs, dk);
      gload16(kN + (r0 + 8) * 64 + cs, dk + 512);
      gload16(vN + r0 * 4096 + cs, dv);
      gload16(vN + (r0 + 8) * 4096 + cs, dv + 512);
    }
    const unsigned short* Kt = KV[cur][0];
    const unsigned short* Vt = KV[cur][1];

    uint2 pp[4][4];
#pragma unroll
    for (int half = 0; half < 2; ++half) {
      f32x4 st[2][4] = {};
#pragma unroll
      for (int kk = 0; kk < 2; ++kk) {
        int cg = kk * 4 + quad;
        bf16x8 kf0 = *(const bf16x8*)(Kt + SWZ(half * 32 + l15, cg));
        bf16x8 kf1 = *(const bf16x8*)(Kt + SWZ(half * 32 + 16 + l15, cg));
#pragma unroll
        for (int qb = 0; qb < 4; ++qb) {
          st[0][qb] = __builtin_amdgcn_mfma_f32_16x16x32_bf16(kf0, qf[qb][kk], st[0][qb], 0, 0, 0);
          st[1][qb] = __builtin_amdgcn_mfma_f32_16x16x32_bf16(kf1, qf[qb][kk], st[1][qb], 0, 0, 0);
        }
      }
#pragma unroll
      for (int kb = 0; kb < 2; ++kb)
#pragma unroll
        for (int qb = 0; qb < 4; ++qb) {
          f32x4 s = st[kb][qb];
          float p0 = fast_exp2(s[0]), p1 = fast_exp2(s[1]);
          float p2 = fast_exp2(s[2]), p3 = fast_exp2(s[3]);
          lsum[qb] += (p0 + p1) + (p2 + p3);
          uint2 d;
          d.x = pack_bf2(p0, p1);
          d.y = pack_bf2(p2, p3);
          pp[qb][half * 2 + kb] = d;
        }
    }

    bf16x8 vf[2][4];
#pragma unroll
    for (int kk = 0; kk < 2; ++kk)
#pragma unroll
      for (int db = 0; db < 4; ++db)
        vf[kk][db] = *(const bf16x8*)(Vt + SWZ(db * 16 + l15, kk * 4 + quad));
#pragma unroll
    for (int qb = 0; qb < 4; ++qb) {
#pragma unroll
      for (int g = 0; g < 4; ++g)
        *(uint2*)(Pw + l15 * LDP + g * 16 + quad * 4) = pp[qb][g];
#pragma unroll
      for (int kk = 0; kk < 2; ++kk) {
        bf16x8 pa = *(const bf16x8*)(Pw + l15 * LDP + kk * 32 + quad * 8);
#pragma unroll
        for (int db = 0; db < 4; ++db)
          o[qb][db] = __builtin_amdgcn_mfma_f32_16x16x32_bf16(pa, vf[kk][db], o[qb][db], 0, 0, 0);
      }
    }
  }

#pragma unroll
  for (int qb = 0; qb < 4; ++qb) {
    lsum[qb] += __shfl_xor(lsum[qb], 16);
    lsum[qb] += __shfl_xor(lsum[qb], 32);
  }

  float* Wf = (float*)(&KV[0][0][0]) + w * 1024;
#pragma unroll
  for (int qb = 0; qb < 4; ++qb) {
#pragma unroll
    for (int db = 0; db < 4; ++db)
#pragma unroll
      for (int r = 0; r < 4; ++r)
        Wf[(quad * 4 + r) * 64 + db * 16 + l15] = o[qb][db][r];
    float inv = 1.0f / lsum[qb];
    float4 x0 = *(float4*)(Wf + l15 * 64 + quad * 8);
    float4 x1 = *(float4*)(Wf + l15 * 64 + quad * 8 + 4);
    float4 x2 = *(float4*)(Wf + l15 * 64 + (quad + 4) * 8);
    float4 x3 = *(float4*)(Wf + l15 * 64 + (quad + 4) * 8 + 4);
    uint4 u0, u1;
    u0.x = pack_bf2(x0.x * inv, x0.y * inv);
    u0.y = pack_bf2(x0.z * inv, x0.w * inv);
    u0.z = pack_bf2(x1.x * inv, x1.y * inv);
    u0.w = pack_bf2(x1.z * inv, x1.w * inv);
    u1.x = pack_bf2(x2.x * inv, x2.y * inv);
    u1.y = pack_bf2(x2.z * inv, x2.w * inv);
    u1.z = pack_bf2(x3.x * inv, x3.y * inv);
    u1.w = pack_bf2(x3.z * inv, x3.w * inv);
    int sg = q0 + qb * 16 + l15;
    int base = (b * 4096 + sg) * 1024 + h * 64;
    *(uint4*)(Ab + base + quad * 8) = u0;
    *(uint4*)(Ab + base + (quad + 4) * 8) = u1;
  }
}

// ---------------- GEMM2: out = Ab @ w_out^T + b_out (fp32 out), BK=64 ----------------
__global__ __launch_bounds__(256) void gemm_out(
    const unsigned short* __restrict__ A,
    const unsigned short* __restrict__ Bt,
    const float* __restrict__ bias,
    float* __restrict__ C) {
  const int K = 1024;
  __shared__ unsigned short As[128 * 64];
  __shared__ unsigned short Bs[128 * 64];
  int tid = threadIdx.x;
  int m0 = blockIdx.x * 128, n0 = blockIdx.y * 128;
  int w = tid >> 6, lane = tid & 63, l15 = lane & 15, quad = lane >> 4;
  int wm = (w & 1) * 64, wn = (w >> 1) * 64;

  f32x4 acc[4][4] = {};

  int rs = w * 32 + (lane >> 3);
  int cs = ((lane & 7) ^ (lane >> 3)) * 8;
  const unsigned short* Ag = A + (m0 + rs) * K + cs;
  const unsigned short* Bg = Bt + (n0 + rs) * K + cs;
  unsigned short* Asl = As + w * 2048;
  unsigned short* Bsl = Bs + w * 2048;

  for (int kt = 0; kt < K; kt += 64) {
    __syncthreads();
#pragma unroll
    for (int i = 0; i < 4; ++i) {
      gload16(Ag + i * 8 * K + kt, Asl + i * 512);
      gload16(Bg + i * 8 * K + kt, Bsl + i * 512);
    }
    __syncthreads();
#pragma unroll
    for (int kk = 0; kk < 2; ++kk) {
      int swk = (((kk * 4 + quad) ^ (l15 & 7))) * 8;
      bf16x8 af[4], bfr[4];
#pragma unroll
      for (int i = 0; i < 4; ++i) af[i] = *(const bf16x8*)(As + (wm + i * 16 + l15) * 64 + swk);
#pragma unroll
      for (int j = 0; j < 4; ++j) bfr[j] = *(const bf16x8*)(Bs + (wn + j * 16 + l15) * 64 + swk);
#pragma unroll
      for (int i = 0; i < 4; ++i)
#pragma unroll
        for (int j = 0; j < 4; ++j)
          acc[i][j] = __builtin_amdgcn_mfma_f32_16x16x32_bf16(af[i], bfr[j], acc[i][j], 0, 0, 0);
    }
  }

#pragma unroll
  for (int j = 0; j < 4; ++j) {
    int n_j = n0 + wn + j * 16 + l15;
    float bv = bias[n_j];
#pragma unroll
    for (int i = 0; i < 4; ++i)
#pragma unroll
      for (int r = 0; r < 4; ++r) {
        int m = m0 + wm + i * 16 + quad * 4 + r;
        C[m * 1024 + n_j] = acc[i][j][r] + bv;
      }
  }
}

// ---------------- launch ----------------
extern "C" void kernel_launch(void* const* d_in, const int* in_sizes, int n_in,
                              void* d_out, int out_size, void* d_ws, size_t ws_size,
                              hipStream_t stream) {
  const float* x     = (const float*)d_in[0];
  const float* w_qkv = (const float*)d_in[1];
  const float* b_qkv = (const float*)d_in[2];
  const float* w_out = (const float*)d_in[3];
  const float* b_out = (const float*)d_in[4];
  float* out = (float*)d_out;
  char* ws = (char*)d_ws;

  unsigned short* wqkvb = (unsigned short*)(ws);              //  6 MB [3072][1024]
  unsigned short* woutb = (unsigned short*)(ws + 6291456);    //  2 MB [1024][1024]
  unsigned short* Qb    = (unsigned short*)(ws + 8388608);    // 16 MB [b,h,s,d] (x SL2E)
  unsigned short* Kb    = (unsigned short*)(ws + 25165824);   // 16 MB [b,h,s,d]
  unsigned short* Vtb   = (unsigned short*)(ws + 41943040);   // 16 MB [b,h,d,s]
  unsigned short* xb    = (unsigned short*)(ws + 58720256);   // 16 MB (reused as Ab)
  unsigned short* Ab    = xb;

  f32_to_bf16_all<<<12288, 256, 0, stream>>>(x, w_qkv, w_out, xb, wqkvb, woutb);
  gemm_qkv<<<dim3(64, 24), 256, 0, stream>>>(xb, wqkvb, b_qkv, Qb, Kb, Vtb);
  attn_k<<<512, 256, 0, stream>>>(Qb, Kb, Vtb, Ab);
  gemm_out<<<dim3(64, 8), 256, 0, stream>>>(Ab, woutb, b_out, out);
}